// Round 1
// baseline (247.372 us; speedup 1.0000x reference)
//
#include <hip/hip_runtime.h>
#include <hip/hip_bf16.h>

// StackedAdapter: out[b] = x[b] + W2[g]^T·relu(W1[g]^T·LN(x[b]) + B1[g]) + B2[g]
// g = domain group of batch b (idx is a disjoint partition of 32 batches into 4 groups of 8).
// B=32, S=512, D=1024, F=2048. 16384 tokens, 4096 per group.

#define S_DIM 512
#define D_DIM 1024
#define F_DIM 2048
#define MPG   4096   // rows (tokens) per group, group-gathered order

typedef __attribute__((ext_vector_type(8))) short  short8;   // 8 bf16 (4 VGPRs)
typedef __attribute__((ext_vector_type(4))) float  f32x4;

__device__ __forceinline__ void gll16(const void* g, void* l) {
  // async global->LDS, 16B/lane; LDS dest is wave-uniform base + lane*16
  __builtin_amdgcn_global_load_lds((__attribute__((address_space(1))) void*)g,
                                   (__attribute__((address_space(3))) void*)l,
                                   16, 0, 0);
}

// ---------------------------------------------------------------------------
// Kernel 1: cast f32 weights to bf16 with transpose: [g][K][N] -> [g][N][K]
// 32x32 LDS tile transpose, 256 threads (32x8), both W1 and W2 in one grid.
// ---------------------------------------------------------------------------
__global__ __launch_bounds__(256) void transpose_cast_kernel(
    const float* __restrict__ W1, const float* __restrict__ W2,
    __hip_bfloat16* __restrict__ W1t, __hip_bfloat16* __restrict__ W2t)
{
  __shared__ float tl[32][33];
  const int bid = blockIdx.x;
  const float* src; __hip_bfloat16* dst;
  int R, C, tr, tc;
  if (bid < 8192) {                 // W1: [4][1024][2048] -> [4][2048][1024]
    const int g = bid >> 11, t = bid & 2047;
    R = 1024; C = 2048; tr = t >> 6; tc = t & 63;
    src = W1 + (size_t)g * R * C;
    dst = W1t + (size_t)g * R * C;
  } else {                          // W2: [4][2048][1024] -> [4][1024][2048]
    const int b2 = bid - 8192;
    const int g = b2 >> 11, t = b2 & 2047;
    R = 2048; C = 1024; tr = t >> 5; tc = t & 31;
    src = W2 + (size_t)g * R * C;
    dst = W2t + (size_t)g * R * C;
  }
  const int tx = threadIdx.x & 31, ty = threadIdx.x >> 5;
  const int r0 = tr * 32, c0 = tc * 32;
#pragma unroll
  for (int i = 0; i < 4; ++i)
    tl[ty + 8 * i][tx] = src[(size_t)(r0 + ty + 8 * i) * C + (c0 + tx)];
  __syncthreads();
#pragma unroll
  for (int i = 0; i < 4; ++i)
    dst[(size_t)(c0 + ty + 8 * i) * R + (r0 + tx)] = __float2bfloat16(tl[tx][ty + 8 * i]);
}

// ---------------------------------------------------------------------------
// Kernel 2: LayerNorm + gather into group-major order, cast to bf16.
// One wave per token; 16 f32 per lane; 64-lane shfl_xor reduce.
// torch semantics: a2*(x-mu)/(std_ddof1 + eps) + b2
// ---------------------------------------------------------------------------
__global__ __launch_bounds__(256) void ln_gather_kernel(
    const float* __restrict__ x, const int* __restrict__ idx,
    const float* __restrict__ G, const float* __restrict__ Bn,
    __hip_bfloat16* __restrict__ Xn)
{
  const int wid  = (blockIdx.x * 256 + threadIdx.x) >> 6;  // 0..16383
  const int lane = threadIdx.x & 63;
  const int g = wid >> 12;          // /4096
  const int r = wid & 4095;
  const int j = r >> 9;             // /512
  const int tok = r & 511;
  const int b = idx[g * 8 + j];

  const float* src = x + ((size_t)b * S_DIM + tok) * D_DIM + lane * 16;
  float4 vq[4];
#pragma unroll
  for (int i = 0; i < 4; ++i) vq[i] = ((const float4*)src)[i];
  const float* va = (const float*)vq;

  float s = 0.f, s2 = 0.f;
#pragma unroll
  for (int i = 0; i < 16; ++i) { s += va[i]; s2 += va[i] * va[i]; }
#pragma unroll
  for (int o = 32; o > 0; o >>= 1) { s += __shfl_xor(s, o); s2 += __shfl_xor(s2, o); }

  const float mu  = s * (1.0f / 1024.0f);
  float var = fmaxf(s2 * (1.0f / 1024.0f) - mu * mu, 0.0f) * (1024.0f / 1023.0f);
  const float rs  = 1.0f / (sqrtf(var) + 1e-6f);

  float4 gq[4], bq[4];
  const float* gp = G  + (size_t)g * D_DIM + lane * 16;
  const float* bp = Bn + (size_t)g * D_DIM + lane * 16;
#pragma unroll
  for (int i = 0; i < 4; ++i) { gq[i] = ((const float4*)gp)[i]; bq[i] = ((const float4*)bp)[i]; }
  const float* ga = (const float*)gq;
  const float* be = (const float*)bq;

  __align__(16) __hip_bfloat16 ob[16];
#pragma unroll
  for (int i = 0; i < 16; ++i)
    ob[i] = __float2bfloat16(ga[i] * (va[i] - mu) * rs + be[i]);

  __hip_bfloat16* dst = Xn + ((size_t)g * MPG + r) * D_DIM + lane * 16;
  ((uint4*)dst)[0] = *(const uint4*)&ob[0];
  ((uint4*)dst)[1] = *(const uint4*)&ob[8];
}

// ---------------------------------------------------------------------------
// Kernels 3/4: bf16 MFMA GEMM, m97 structure.
// C[16384][N] = A[16384][K] x Bw[g][N][K]^T  (+bias, then relu->bf16  OR
//                                             +bias+residual, scatter->f32)
// 128x128 tile, BK=64, 4 waves (2x2), 4x4 frags of 16x16x32.
// M-tiles never cross a group (4096 % 128 == 0) nor a source batch (512%128==0).
// ---------------------------------------------------------------------------
template <bool SECOND>
__global__ __launch_bounds__(256) void gemm_kernel(
    const __hip_bfloat16* __restrict__ A,
    const __hip_bfloat16* __restrict__ Bw,
    const float* __restrict__ bias,
    const float* __restrict__ xres,
    const int* __restrict__ idx,
    __hip_bfloat16* __restrict__ obf,
    float* __restrict__ of32,
    const int N, const int K)
{
  __shared__ __hip_bfloat16 As[128 * 64];
  __shared__ __hip_bfloat16 Bs[128 * 64];

  const int ntile = N >> 7;
  const int mt = blockIdx.x / ntile;
  const int nt = blockIdx.x % ntile;
  const int g  = mt >> 5;                 // 4096 rows / 128 = 32 tiles per group
  const int tid = threadIdx.x;
  const int w = tid >> 6, lane = tid & 63;
  const int wm = w >> 1, wn = w & 1;

  const __hip_bfloat16* Ab = A + (size_t)mt * 128 * K;
  const __hip_bfloat16* Bb = Bw + ((size_t)g * N + (size_t)nt * 128) * K;
  const int l8 = lane >> 3, l7 = lane & 7;
  const int srow = w * 32 + l8;           // staging row (+= i*8)

  f32x4 acc[4][4] = {};

  for (int kt = 0; kt < K; kt += 64) {
    __syncthreads();                      // previous compute done before overwrite
#pragma unroll
    for (int i = 0; i < 4; ++i) {
      gll16(Ab + (size_t)(srow + i * 8) * K + kt + l7 * 8, &As[(w * 32 + i * 8) * 64]);
      gll16(Bb + (size_t)(srow + i * 8) * K + kt + l7 * 8, &Bs[(w * 32 + i * 8) * 64]);
    }
    __syncthreads();                      // compiler drains vmcnt before barrier
#pragma unroll
    for (int kk = 0; kk < 2; ++kk) {
      const int ko = kk * 32 + (lane >> 4) * 8;
      short8 af[4], bfr[4];
#pragma unroll
      for (int m = 0; m < 4; ++m)
        af[m] = *(const short8*)&As[(wm * 64 + m * 16 + (lane & 15)) * 64 + ko];
#pragma unroll
      for (int n = 0; n < 4; ++n)
        bfr[n] = *(const short8*)&Bs[(wn * 64 + n * 16 + (lane & 15)) * 64 + ko];
#pragma unroll
      for (int m = 0; m < 4; ++m)
#pragma unroll
        for (int n = 0; n < 4; ++n)
          acc[m][n] = __builtin_amdgcn_mfma_f32_16x16x32_bf16(af[m], bfr[n], acc[m][n], 0, 0, 0);
    }
  }

  // C/D layout: col = lane&15, row = (lane>>4)*4 + i   [measured m89/m91]
  const int cc = lane & 15;
  const int cr = (lane >> 4) * 4;

  float bv[4];
#pragma unroll
  for (int n = 0; n < 4; ++n)
    bv[n] = bias[(size_t)g * N + nt * 128 + wn * 64 + n * 16 + cc];

  if constexpr (!SECOND) {
    // bias + relu -> bf16 H1 (group-gathered row order)
#pragma unroll
    for (int m = 0; m < 4; ++m) {
      const int grow0 = mt * 128 + wm * 64 + m * 16 + cr;
#pragma unroll
      for (int n = 0; n < 4; ++n) {
        const int gcol = nt * 128 + wn * 64 + n * 16 + cc;
#pragma unroll
        for (int i = 0; i < 4; ++i) {
          const float v = fmaxf(acc[m][n][i] + bv[n], 0.0f);
          obf[(size_t)(grow0 + i) * N + gcol] = __float2bfloat16(v);
        }
      }
    }
  } else {
    // bias + residual, scatter back to original batch position (f32 out)
    const int rbase = (mt & 31) * 128;            // row-in-group base of this tile
    const int b = idx[g * 8 + (rbase >> 9)];      // whole tile inside one batch
    const size_t orow0 = (size_t)b * S_DIM * (size_t)D_DIM;
#pragma unroll
    for (int m = 0; m < 4; ++m) {
      const int rloc = rbase + wm * 64 + m * 16 + cr;
#pragma unroll
      for (int n = 0; n < 4; ++n) {
        const int gcol = nt * 128 + wn * 64 + n * 16 + cc;
#pragma unroll
        for (int i = 0; i < 4; ++i) {
          const int tok = (rloc + i) & 511;
          const size_t off = orow0 + (size_t)tok * D_DIM + gcol;
          of32[off] = acc[m][n][i] + bv[n] + xres[off];
        }
      }
    }
  }
}

// ---------------------------------------------------------------------------
extern "C" void kernel_launch(void* const* d_in, const int* in_sizes, int n_in,
                              void* d_out, int out_size, void* d_ws, size_t ws_size,
                              hipStream_t stream) {
  const float* x  = (const float*)d_in[0];
  const int*   idx = (const int*)d_in[1];
  const float* W1 = (const float*)d_in[2];
  const float* B1 = (const float*)d_in[3];
  const float* W2 = (const float*)d_in[4];
  const float* B2 = (const float*)d_in[5];
  const float* G  = (const float*)d_in[6];
  const float* Bn = (const float*)d_in[7];
  float* out = (float*)d_out;

  char* ws = (char*)d_ws;
  __hip_bfloat16* Xn  = (__hip_bfloat16*)(ws);                    // 16384*1024*2 = 32 MiB
  __hip_bfloat16* W1t = (__hip_bfloat16*)(ws + 33554432);         // 4*2048*1024*2 = 16 MiB
  __hip_bfloat16* W2t = (__hip_bfloat16*)(ws + 50331648);         // 16 MiB
  __hip_bfloat16* H1  = (__hip_bfloat16*)(ws + 67108864);         // 16384*2048*2 = 64 MiB
  // total ws use: 128 MiB

  transpose_cast_kernel<<<dim3(16384), dim3(256), 0, stream>>>(W1, W2, W1t, W2t);
  ln_gather_kernel<<<dim3(4096), dim3(256), 0, stream>>>(x, idx, G, Bn, Xn);
  gemm_kernel<false><<<dim3(2048), dim3(256), 0, stream>>>(
      Xn, W1t, B1, nullptr, nullptr, H1, nullptr, F_DIM, D_DIM);
  gemm_kernel<true><<<dim3(1024), dim3(256), 0, stream>>>(
      H1, W2t, B2, x, idx, nullptr, out, D_DIM, F_DIM);
}

// Round 2
// 187.894 us; speedup vs baseline: 1.3166x; 1.3166x over previous
//
#include <hip/hip_runtime.h>
#include <hip/hip_bf16.h>

// StackedAdapter: out[b] = x[b] + W2[g]^T·relu(W1[g]^T·LN(x[b]) + B1[g]) + B2[g]
// B=32, S=512, D=1024, F=2048. 16384 tokens, 4096 per group, 4 groups.

#define S_DIM 512
#define D_DIM 1024
#define F_DIM 2048
#define MPG   4096

typedef __attribute__((ext_vector_type(8))) short  short8;   // 8 bf16
typedef __attribute__((ext_vector_type(4))) float  f32x4;

__device__ __forceinline__ void gll16(const void* g, void* l) {
  __builtin_amdgcn_global_load_lds((__attribute__((address_space(1))) void*)g,
                                   (__attribute__((address_space(3))) void*)l,
                                   16, 0, 0);
}
#define BAR()  asm volatile("s_barrier" ::: "memory")
#define VMC4() asm volatile("s_waitcnt vmcnt(4)" ::: "memory")
#define LGKM0() asm volatile("s_waitcnt lgkmcnt(0)" ::: "memory")

// ---------------------------------------------------------------------------
// Kernel 1: cast f32 weights to bf16 with transpose: [g][K][N] -> [g][N][K]
// ---------------------------------------------------------------------------
__global__ __launch_bounds__(256) void transpose_cast_kernel(
    const float* __restrict__ W1, const float* __restrict__ W2,
    __hip_bfloat16* __restrict__ W1t, __hip_bfloat16* __restrict__ W2t)
{
  __shared__ float tl[32][33];
  const int bid = blockIdx.x;
  const float* src; __hip_bfloat16* dst;
  int R, C, tr, tc;
  if (bid < 8192) {                 // W1: [4][1024][2048] -> [4][2048][1024]
    const int g = bid >> 11, t = bid & 2047;
    R = 1024; C = 2048; tr = t >> 6; tc = t & 63;
    src = W1 + (size_t)g * R * C;
    dst = W1t + (size_t)g * R * C;
  } else {                          // W2: [4][2048][1024] -> [4][1024][2048]
    const int b2 = bid - 8192;
    const int g = b2 >> 11, t = b2 & 2047;
    R = 2048; C = 1024; tr = t >> 5; tc = t & 31;
    src = W2 + (size_t)g * R * C;
    dst = W2t + (size_t)g * R * C;
  }
  const int tx = threadIdx.x & 31, ty = threadIdx.x >> 5;
  const int r0 = tr * 32, c0 = tc * 32;
#pragma unroll
  for (int i = 0; i < 4; ++i)
    tl[ty + 8 * i][tx] = src[(size_t)(r0 + ty + 8 * i) * C + (c0 + tx)];
  __syncthreads();
#pragma unroll
  for (int i = 0; i < 4; ++i)
    dst[(size_t)(c0 + ty + 8 * i) * R + (r0 + tx)] = __float2bfloat16(tl[tx][ty + 8 * i]);
}

// ---------------------------------------------------------------------------
// Kernel 2: LayerNorm + gather into group-major order, cast to bf16.
// ---------------------------------------------------------------------------
__global__ __launch_bounds__(256) void ln_gather_kernel(
    const float* __restrict__ x, const int* __restrict__ idx,
    const float* __restrict__ G, const float* __restrict__ Bn,
    __hip_bfloat16* __restrict__ Xn)
{
  const int wid  = (blockIdx.x * 256 + threadIdx.x) >> 6;
  const int lane = threadIdx.x & 63;
  const int g = wid >> 12;
  const int r = wid & 4095;
  const int j = r >> 9;
  const int tok = r & 511;
  const int b = idx[g * 8 + j];

  const float* src = x + ((size_t)b * S_DIM + tok) * D_DIM + lane * 16;
  float4 vq[4];
#pragma unroll
  for (int i = 0; i < 4; ++i) vq[i] = ((const float4*)src)[i];
  const float* va = (const float*)vq;

  float s = 0.f, s2 = 0.f;
#pragma unroll
  for (int i = 0; i < 16; ++i) { s += va[i]; s2 += va[i] * va[i]; }
#pragma unroll
  for (int o = 32; o > 0; o >>= 1) { s += __shfl_xor(s, o); s2 += __shfl_xor(s2, o); }

  const float mu  = s * (1.0f / 1024.0f);
  float var = fmaxf(s2 * (1.0f / 1024.0f) - mu * mu, 0.0f) * (1024.0f / 1023.0f);
  const float rs  = 1.0f / (sqrtf(var) + 1e-6f);

  float4 gq[4], bq[4];
  const float* gp = G  + (size_t)g * D_DIM + lane * 16;
  const float* bp = Bn + (size_t)g * D_DIM + lane * 16;
#pragma unroll
  for (int i = 0; i < 4; ++i) { gq[i] = ((const float4*)gp)[i]; bq[i] = ((const float4*)bp)[i]; }
  const float* ga = (const float*)gq;
  const float* be = (const float*)bq;

  __align__(16) __hip_bfloat16 ob[16];
#pragma unroll
  for (int i = 0; i < 16; ++i)
    ob[i] = __float2bfloat16(ga[i] * (va[i] - mu) * rs + be[i]);

  __hip_bfloat16* dst = Xn + ((size_t)g * MPG + r) * D_DIM + lane * 16;
  ((uint4*)dst)[0] = *(const uint4*)&ob[0];
  ((uint4*)dst)[1] = *(const uint4*)&ob[8];
}

// ---------------------------------------------------------------------------
// Kernels 3/4: bf16 MFMA GEMM, 256x256 tile, BK=64, 8 waves (2Mx4N),
// 4-phase/K-tile schedule with counted vmcnt(4), permuted LDS planes.
//
// LDS per buffer: A then B, each as 2 K-half planes of [128 lines][128 B].
// Plane stores row-pair per 128-B line; 16-B slot permutation:
//   phys_slot(r, s) = ((r&1)*4 + s) ^ ((r>>1)&7)        (s = 16B slot, 0..3)
// ds_read_b128 of a column slice then hits 8 distinct slots per 8 rows
// (2 lanes/bank = free). global_load_lds writes linearly; the global source
// address carries the inverse permutation (both-sides-or-neither, rule 21).
// ---------------------------------------------------------------------------
template <bool SECOND>
__global__ __launch_bounds__(512, 2) void gemm_kernel(
    const __hip_bfloat16* __restrict__ A,
    const __hip_bfloat16* __restrict__ Bw,
    const float* __restrict__ bias,
    const float* __restrict__ xres,
    const int* __restrict__ idx,
    __hip_bfloat16* __restrict__ obf,
    float* __restrict__ of32,
    const int N, const int K, const int NT)
{
  extern __shared__ char lds[];     // 131072 bytes: 2 buffers x (A 32K + B 32K)
  const int ntile = N >> 8;
  const int nwg = gridDim.x;
  const int bid0 = blockIdx.x;
  const int bid = (bid0 & 7) * (nwg >> 3) + (bid0 >> 3);   // XCD-contiguous
  const int mt = bid / ntile, nt = bid % ntile;
  const int g  = mt >> 4;                                  // 16 M-tiles per group
  const int tid = threadIdx.x;
  const int w = tid >> 6, lane = tid & 63;
  const int wm = w >> 2, wn = w & 3;

  const __hip_bfloat16* Ab = A + (size_t)mt * 256 * K;
  const __hip_bfloat16* Bb = Bw + ((size_t)g * N + (size_t)nt * 256) * K;

  // --- staging decode (per lane): inverse of the slot permutation ---
  const int sp   = (lane & 7) ^ ((lane >> 3) & 7);
  const int srow = 2 * (lane >> 3) + (sp >> 2);   // row offset within 16-row chunk
  const int skof = (sp & 3) * 8;                  // k-element offset within k-half

  // --- ds_read lane constant (phys slot for this lane) ---
  const int l15 = lane & 15, sl = lane >> 4;
  const int slot_phys = (((l15 & 1) << 2) + sl) ^ ((l15 >> 1) & 7);
  const int lane_c = ((l15 >> 1) << 7) + (slot_phys << 4);

  f32x4 acc[8][4] = {};

  // stage one 16 KB plane (mat: 0=A,1=B; khalf kh) of K-tile tn into buffer bufw
  auto stage = [&](int bufw, int mat, int kh, int tn) {
    const __hip_bfloat16* src = mat ? Bb : Ab;
    const size_t gk = (size_t)tn * 64 + kh * 32 + skof;
    char* dst = lds + bufw * 65536 + mat * 32768 + kh * 16384 + w * 2048;
    const int r0 = w * 32 + srow;
    gll16(src + (size_t)r0 * K + gk, dst);
    gll16(src + (size_t)(r0 + 16) * K + gk, dst + 1024);
  };

  // prologue: stage K-tile 0 (4 planes) into buffer 0
  stage(0, 0, 0, 0);   // A kh0
  stage(0, 1, 0, 0);   // B kh0
  stage(0, 0, 1, 0);   // A kh1
  stage(0, 1, 1, 0);   // B kh1

  short8 bfrag[4];

#define PHASE(KH, MH, SMAT, SKH, DOVM)                                          \
  {                                                                             \
    __builtin_amdgcn_sched_barrier(0);                                          \
    if (DOVM) VMC4();                                                           \
    BAR();                                                                      \
    const char* Abase = lds + bufb + (KH) * 16384 + wm * 8192 + lane_c;         \
    short8 afr[4];                                                              \
    _Pragma("unroll") for (int mm = 0; mm < 4; ++mm)                            \
      afr[mm] = *(const short8*)(Abase + ((MH) * 4 + mm) * 1024);               \
    if ((MH) == 0) {                                                            \
      const char* Bbase = lds + bufb + 32768 + (KH) * 16384 + wn * 4096 + lane_c; \
      _Pragma("unroll") for (int n = 0; n < 4; ++n)                             \
        bfrag[n] = *(const short8*)(Bbase + n * 1024);                          \
    }                                                                           \
    stage(bufn, SMAT, SKH, tn);                                                 \
    LGKM0();                                                                    \
    __builtin_amdgcn_sched_barrier(0);                                          \
    __builtin_amdgcn_s_setprio(1);                                              \
    _Pragma("unroll") for (int mm = 0; mm < 4; ++mm)                            \
      _Pragma("unroll") for (int n = 0; n < 4; ++n)                             \
        acc[(MH) * 4 + mm][n] = __builtin_amdgcn_mfma_f32_16x16x32_bf16(        \
            afr[mm], bfrag[n], acc[(MH) * 4 + mm][n], 0, 0, 0);                 \
    __builtin_amdgcn_s_setprio(0);                                              \
  }

  for (int t = 0; t < NT; ++t) {
    const int bufb = (t & 1) * 65536;
    const int bufn = (t & 1) ^ 1;
    const int tn = (t + 1 == NT) ? 0 : t + 1;   // wrap: dummy re-stage, never read
    PHASE(0, 0, 0, 0, 1)   // compute kh0, M-half 0 ; stage (t+1, A kh0) ; vmcnt(4)
    PHASE(0, 1, 1, 0, 0)   // compute kh0, M-half 1 ; stage (t+1, B kh0)
    PHASE(1, 0, 0, 1, 1)   // compute kh1, M-half 0 ; stage (t+1, A kh1) ; vmcnt(4)
    PHASE(1, 1, 1, 1, 0)   // compute kh1, M-half 1 ; stage (t+1, B kh1)
  }
#undef PHASE

  // C/D layout: col = lane&15, row = (lane>>4)*4 + i   [m89/m91]
  const int cc  = lane & 15;
  const int cr4 = (lane >> 4) * 4;

  float bv[4];
#pragma unroll
  for (int n = 0; n < 4; ++n)
    bv[n] = bias[(size_t)g * N + nt * 256 + wn * 64 + n * 16 + cc];

  if constexpr (!SECOND) {
#pragma unroll
    for (int m = 0; m < 8; ++m) {
      const int grow0 = mt * 256 + wm * 128 + m * 16 + cr4;
#pragma unroll
      for (int n = 0; n < 4; ++n) {
        const int gcol = nt * 256 + wn * 64 + n * 16 + cc;
#pragma unroll
        for (int i = 0; i < 4; ++i) {
          const float v = fmaxf(acc[m][n][i] + bv[n], 0.0f);
          obf[(size_t)(grow0 + i) * N + gcol] = __float2bfloat16(v);
        }
      }
    }
  } else {
    const int rbase = (mt & 15) * 256;            // row-in-group base of tile
    const int b = idx[g * 8 + (rbase >> 9)];      // tile never crosses a batch
    const size_t ob = (size_t)b * S_DIM * D_DIM;
#pragma unroll
    for (int m = 0; m < 8; ++m) {
      const int rloc = rbase + wm * 128 + m * 16 + cr4;
#pragma unroll
      for (int n = 0; n < 4; ++n) {
        const int gcol = nt * 256 + wn * 64 + n * 16 + cc;
#pragma unroll
        for (int i = 0; i < 4; ++i) {
          const int tok = (rloc + i) & 511;
          const size_t off = ob + (size_t)tok * D_DIM + gcol;
          of32[off] = acc[m][n][i] + bv[n] + xres[off];
        }
      }
    }
  }
}

// ---------------------------------------------------------------------------
extern "C" void kernel_launch(void* const* d_in, const int* in_sizes, int n_in,
                              void* d_out, int out_size, void* d_ws, size_t ws_size,
                              hipStream_t stream) {
  const float* x  = (const float*)d_in[0];
  const int*   idx = (const int*)d_in[1];
  const float* W1 = (const float*)d_in[2];
  const float* B1 = (const float*)d_in[3];
  const float* W2 = (const float*)d_in[4];
  const float* B2 = (const float*)d_in[5];
  const float* G  = (const float*)d_in[6];
  const float* Bn = (const float*)d_in[7];
  float* out = (float*)d_out;

  char* ws = (char*)d_ws;
  __hip_bfloat16* Xn  = (__hip_bfloat16*)(ws);                    // 32 MiB
  __hip_bfloat16* W1t = (__hip_bfloat16*)(ws + 33554432);         // 16 MiB
  __hip_bfloat16* W2t = (__hip_bfloat16*)(ws + 50331648);         // 16 MiB
  __hip_bfloat16* H1  = (__hip_bfloat16*)(ws + 67108864);         // 64 MiB

  (void)hipFuncSetAttribute((const void*)gemm_kernel<false>,
                            hipFuncAttributeMaxDynamicSharedMemorySize, 131072);
  (void)hipFuncSetAttribute((const void*)gemm_kernel<true>,
                            hipFuncAttributeMaxDynamicSharedMemorySize, 131072);

  transpose_cast_kernel<<<dim3(16384), dim3(256), 0, stream>>>(W1, W2, W1t, W2t);
  ln_gather_kernel<<<dim3(4096), dim3(256), 0, stream>>>(x, idx, G, Bn, Xn);
  gemm_kernel<false><<<dim3(512), dim3(512), 131072, stream>>>(
      Xn, W1t, B1, nullptr, nullptr, H1, nullptr, F_DIM, D_DIM, 16);
  gemm_kernel<true><<<dim3(256), dim3(512), 131072, stream>>>(
      H1, W2t, B2, x, idx, nullptr, out, D_DIM, F_DIM, 32);
}